// Round 1
// baseline (1183.255 us; speedup 1.0000x reference)
//
#include <hip/hip_runtime.h>

#define N_NODES  100000
#define N_EDGES  1600000
#define N_GRAPHS 64

__device__ __forceinline__ float lrelu(float v) { return v > 0.f ? v : 0.2f * v; }
__device__ __forceinline__ float elu_f(float v) { return v > 0.f ? v : __expf(v) - 1.f; }

// ---- tiny precompute: ws1[h] = <W1[h,:], att_src1[h,:]>, wd1[h] = <W1[h,:], att_dst1[h,:]>
__global__ void k_ws1(const float* __restrict__ W1, const float* __restrict__ as1,
                      const float* __restrict__ ad1, float* __restrict__ wsd) {
    int h = threadIdx.x;
    if (h < 8) {
        float s = 0.f, d = 0.f;
        for (int c = 0; c < 8; ++c) {
            float w = W1[h * 8 + c];
            s += w * as1[h * 8 + c];
            d += w * ad1[h * 8 + c];
        }
        wsd[h] = s;
        wsd[8 + h] = d;
    }
}

// ---- CSR build: in-degree histogram
__global__ void k_deg(const int* __restrict__ dst, int* __restrict__ deg) {
    int e = blockIdx.x * blockDim.x + threadIdx.x;
    if (e < N_EDGES) atomicAdd(&deg[dst[e]], 1);
}

__global__ void k_cnt(const int* __restrict__ batch, int* __restrict__ cnt) {
    int n = blockIdx.x * blockDim.x + threadIdx.x;
    if (n < N_NODES) atomicAdd(&cnt[batch[n]], 1);
}

// ---- exclusive scan (3-kernel, block size 256)
__global__ void k_scan1(const int* __restrict__ deg, int* __restrict__ off,
                        int* __restrict__ bsums) {
    __shared__ int sm[256];
    int t = threadIdx.x;
    int i = blockIdx.x * 256 + t;
    int v = (i < N_NODES) ? deg[i] : 0;
    sm[t] = v;
    __syncthreads();
    for (int d = 1; d < 256; d <<= 1) {
        int add = (t >= d) ? sm[t - d] : 0;
        __syncthreads();
        sm[t] += add;
        __syncthreads();
    }
    if (i < N_NODES) off[i] = sm[t] - v;  // block-local exclusive
    if (t == 255) bsums[blockIdx.x] = sm[255];
}

__global__ void k_scan2(const int* __restrict__ bsums, int* __restrict__ bsumoff, int nb) {
    __shared__ int sm[512];
    int t = threadIdx.x;
    int v = (t < nb) ? bsums[t] : 0;
    sm[t] = v;
    __syncthreads();
    for (int d = 1; d < 512; d <<= 1) {
        int add = (t >= d) ? sm[t - d] : 0;
        __syncthreads();
        sm[t] += add;
        __syncthreads();
    }
    if (t < nb) bsumoff[t] = sm[t] - v;  // exclusive block offsets
}

__global__ void k_scan3(int* __restrict__ off, const int* __restrict__ bsumoff) {
    int i = blockIdx.x * blockDim.x + threadIdx.x;
    if (i < N_NODES) off[i] += bsumoff[i >> 8];
    if (i == 0) off[N_NODES] = N_EDGES;
}

// ---- CSR fill (src ids bucketed by dst)
__global__ void k_fill(const int* __restrict__ src, const int* __restrict__ dst,
                       const int* __restrict__ off, int* __restrict__ cursor,
                       int* __restrict__ csr) {
    int e = blockIdx.x * blockDim.x + threadIdx.x;
    if (e < N_EDGES) {
        int d = dst[e];
        int p = atomicAdd(&cursor[d], 1);
        csr[off[d] + p] = src[e];
    }
}

// ---- Layer 1: rank-1 GAT. One thread per destination node -> s1[n,h] = sum alpha * x[src]
__global__ void k_layer1(const float* __restrict__ x, const float* __restrict__ wsd,
                         const int* __restrict__ off, const int* __restrict__ csr,
                         float* __restrict__ s1) {
    int n = blockIdx.x * blockDim.x + threadIdx.x;
    if (n >= N_NODES) return;
    float xn = x[n];
    float ws[8], wd[8];
#pragma unroll
    for (int h = 0; h < 8; ++h) { ws[h] = wsd[h]; wd[h] = wsd[8 + h]; }
    float num[8], den[8];
#pragma unroll
    for (int h = 0; h < 8; ++h) {  // self loop (src = n)
        float w = __expf(lrelu(xn * ws[h] + xn * wd[h]));
        den[h] = w;
        num[h] = w * xn;
    }
    int b = off[n], e = off[n + 1];
    for (int i = b; i < e; ++i) {
        int s = csr[i];
        float xs = x[s];
#pragma unroll
        for (int h = 0; h < 8; ++h) {
            float w = __expf(lrelu(xs * ws[h] + xn * wd[h]));
            den[h] += w;
            num[h] += w * xs;
        }
    }
#pragma unroll
    for (int h = 0; h < 8; ++h) s1[n * 8 + h] = num[h] / den[h];
}

// ---- Fused: h1_act (ELU) regeneration + [N,64]@[64,128] GEMM + a_src2/a_dst2 epilogue.
// One wave per node; lane l owns output cols j=l and j=64+l.
__global__ __launch_bounds__(256) void k_gemm(
    const float* __restrict__ s1, const float* __restrict__ W1, const float* __restrict__ b1,
    const float* __restrict__ W2, const float* __restrict__ as2, const float* __restrict__ ad2,
    float* __restrict__ h2, float* __restrict__ asrc2, float* __restrict__ adst2) {
    __shared__ float smW2[64 * 128];
    int t = threadIdx.x;
    for (int idx = t; idx < 64 * 128; idx += 256) smW2[idx] = W2[idx];
    __syncthreads();
    int wid = t >> 6, l = t & 63;
    int n = blockIdx.x * 4 + wid;
    if (n >= N_NODES) return;

    // a[k] for k=l: h1_act[n,l] = elu(s1[n, l>>3] * W1[l] + b1[l])
    float a = elu_f(s1[n * 8 + (l >> 3)] * W1[l] + b1[l]);

    float acc0 = 0.f, acc1 = 0.f;
#pragma unroll
    for (int k = 0; k < 64; ++k) {
        float ak = __shfl(a, k, 64);
        acc0 += ak * smW2[k * 128 + l];
        acc1 += ak * smW2[k * 128 + 64 + l];
    }
    h2[n * 128 + l] = acc0;
    h2[n * 128 + 64 + l] = acc1;

    // a_src2[n,h] = sum_c h2[n,h*16+c]*att_src2[h,c]; flat att index for lane l is l (slot A), l+64 (slot B)
    float pSA = acc0 * as2[l];
    float pSB = acc1 * as2[64 + l];
    float pDA = acc0 * ad2[l];
    float pDB = acc1 * ad2[64 + l];
#pragma unroll
    for (int d = 1; d < 16; d <<= 1) {
        pSA += __shfl_xor(pSA, d, 64);
        pSB += __shfl_xor(pSB, d, 64);
        pDA += __shfl_xor(pDA, d, 64);
        pDB += __shfl_xor(pDB, d, 64);
    }
    if ((l & 15) == 0) {
        int h = l >> 4;
        asrc2[n * 8 + h]     = pSA;
        asrc2[n * 8 + 4 + h] = pSB;
        adst2[n * 8 + h]     = pDA;
        adst2[n * 8 + 4 + h] = pDB;
    }
}

// ---- Layer 2 aggregation + head-mean + pooled atomic accumulation.
// One wave per destination node; lane l owns (h=l>>4, c=l&15) and (h+4, c).
__global__ __launch_bounds__(256) void k_layer2(
    const float* __restrict__ h2, const float* __restrict__ asrc2,
    const float* __restrict__ adst2, const int* __restrict__ off,
    const int* __restrict__ csr, const int* __restrict__ batch,
    float* __restrict__ pool) {
    int t = threadIdx.x;
    int wid = t >> 6, l = t & 63;
    int n = blockIdx.x * 4 + wid;
    if (n >= N_NODES) return;
    int hA = l >> 4;
    float adA = adst2[n * 8 + hA];
    float adB = adst2[n * 8 + 4 + hA];

    // self loop
    float wA = __expf(lrelu(asrc2[n * 8 + hA] + adA));
    float wB = __expf(lrelu(asrc2[n * 8 + 4 + hA] + adB));
    float accA = wA * h2[n * 128 + l];
    float accB = wB * h2[n * 128 + 64 + l];
    float denA = wA, denB = wB;

    int b = off[n], e = off[n + 1];
    for (int i = b; i < e; ++i) {
        int s = csr[i];
        float eA = __expf(lrelu(asrc2[s * 8 + hA] + adA));
        float eB = __expf(lrelu(asrc2[s * 8 + 4 + hA] + adB));
        accA += eA * h2[s * 128 + l];
        accB += eB * h2[s * 128 + 64 + l];
        denA += eA;
        denB += eB;
    }
    float v = accA / denA + accB / denB;  // two of the 8 heads for channel c
    v += __shfl_xor(v, 16, 64);
    v += __shfl_xor(v, 32, 64);
    v *= 0.125f;  // mean over 8 heads
    if (l < 16) {
        int g = batch[n];
        atomicAdd(&pool[g * 16 + l], v);
    }
}

// ---- final: pooled mean (+b2) @ Wfc + bfc -> [64,4]
__global__ void k_final(const float* __restrict__ pool, const int* __restrict__ cnt,
                        const float* __restrict__ b2, const float* __restrict__ Wfc,
                        const float* __restrict__ bfc, float* __restrict__ out) {
    int t = threadIdx.x;
    int g = t >> 2, k = t & 3;
    float c = (float)(cnt[g] > 0 ? cnt[g] : 1);
    float acc = bfc[k];
#pragma unroll
    for (int ci = 0; ci < 16; ++ci)
        acc += (pool[g * 16 + ci] / c + b2[ci]) * Wfc[ci * 4 + k];
    out[g * 4 + k] = acc;
}

extern "C" void kernel_launch(void* const* d_in, const int* in_sizes, int n_in,
                              void* d_out, int out_size, void* d_ws, size_t ws_size,
                              hipStream_t stream) {
    const float* x   = (const float*)d_in[0];
    const float* W1  = (const float*)d_in[1];
    const float* as1 = (const float*)d_in[2];
    const float* ad1 = (const float*)d_in[3];
    const float* b1  = (const float*)d_in[4];
    const float* W2  = (const float*)d_in[5];
    const float* as2 = (const float*)d_in[6];
    const float* ad2 = (const float*)d_in[7];
    const float* b2  = (const float*)d_in[8];
    const float* Wfc = (const float*)d_in[9];
    const float* bfc = (const float*)d_in[10];
    const int* ei    = (const int*)d_in[11];
    const int* batch = (const int*)d_in[12];
    const int* srcv  = ei;             // edge_index[0]
    const int* dstv  = ei + N_EDGES;   // edge_index[1]

    char* ws = (char*)d_ws;
    size_t o = 0;
    auto alloc = [&](size_t bytes) {
        void* p = ws + o;
        o += (bytes + 255) & ~(size_t)255;
        return p;
    };
    // zero-region first (one memset): deg, cursor, cnt, pool
    int*   deg     = (int*)alloc((size_t)N_NODES * 4);
    int*   cursor  = (int*)alloc((size_t)N_NODES * 4);
    int*   cnt     = (int*)alloc(64 * 4);
    float* pool    = (float*)alloc(64 * 16 * 4);
    size_t zbytes  = o;
    int*   off     = (int*)alloc((size_t)(N_NODES + 1) * 4);
    int*   bsums   = (int*)alloc(512 * 4);
    int*   bsumoff = (int*)alloc(512 * 4);
    int*   csr     = (int*)alloc((size_t)N_EDGES * 4);
    float* s1      = (float*)alloc((size_t)N_NODES * 8 * 4);
    float* h2      = (float*)alloc((size_t)N_NODES * 128 * 4);
    float* asrc2   = (float*)alloc((size_t)N_NODES * 8 * 4);
    float* adst2   = (float*)alloc((size_t)N_NODES * 8 * 4);
    float* wsd     = (float*)alloc(16 * 4);

    hipMemsetAsync(d_ws, 0, zbytes, stream);

    int nbN = (N_NODES + 255) / 256;   // 391
    int nbE = (N_EDGES + 255) / 256;

    k_ws1<<<1, 64, 0, stream>>>(W1, as1, ad1, wsd);
    k_deg<<<nbE, 256, 0, stream>>>(dstv, deg);
    k_cnt<<<nbN, 256, 0, stream>>>(batch, cnt);
    k_scan1<<<nbN, 256, 0, stream>>>(deg, off, bsums);
    k_scan2<<<1, 512, 0, stream>>>(bsums, bsumoff, nbN);
    k_scan3<<<nbN, 256, 0, stream>>>(off, bsumoff);
    k_fill<<<nbE, 256, 0, stream>>>(srcv, dstv, off, cursor, csr);
    k_layer1<<<nbN, 256, 0, stream>>>(x, wsd, off, csr, s1);
    k_gemm<<<N_NODES / 4, 256, 0, stream>>>(s1, W1, b1, W2, as2, ad2, h2, asrc2, adst2);
    k_layer2<<<N_NODES / 4, 256, 0, stream>>>(h2, asrc2, adst2, off, csr, batch, pool);
    k_final<<<1, 256, 0, stream>>>(pool, cnt, b2, Wfc, bfc, (float*)d_out);
}

// Round 2
// 647.029 us; speedup vs baseline: 1.8288x; 1.8288x over previous
//
#include <hip/hip_runtime.h>

#define N_NODES  100000
#define N_EDGES  1600000
#define N_GRAPHS 64

__device__ __forceinline__ float lrelu(float v) { return v > 0.f ? v : 0.2f * v; }
__device__ __forceinline__ float elu_f(float v) { return v > 0.f ? v : __expf(v) - 1.f; }

// ---- tiny precompute: ws1[h] = <W1[h,:], att_src1[h,:]>, wd1[h] = <W1[h,:], att_dst1[h,:]>
__global__ void k_ws1(const float* __restrict__ W1, const float* __restrict__ as1,
                      const float* __restrict__ ad1, float* __restrict__ wsd) {
    int h = threadIdx.x;
    if (h < 8) {
        float s = 0.f, d = 0.f;
        for (int c = 0; c < 8; ++c) {
            float w = W1[h * 8 + c];
            s += w * as1[h * 8 + c];
            d += w * ad1[h * 8 + c];
        }
        wsd[h] = s;
        wsd[8 + h] = d;
    }
}

// ---- CSR build: in-degree histogram (random dst -> low contention, ok as-is)
__global__ void k_deg(const int* __restrict__ dst, int* __restrict__ deg) {
    int e = blockIdx.x * blockDim.x + threadIdx.x;
    if (e < N_EDGES) atomicAdd(&deg[dst[e]], 1);
}

// ---- graph-size histogram via LDS (batch is sorted -> same-address global atomics
// would serialize; LDS histogram reduces to ~1-2 global atomics per block)
__global__ void k_cnt(const int* __restrict__ batch, int* __restrict__ cnt) {
    __shared__ int h[N_GRAPHS];
    int t = threadIdx.x;
    if (t < N_GRAPHS) h[t] = 0;
    __syncthreads();
    int n = blockIdx.x * blockDim.x + t;
    if (n < N_NODES) atomicAdd(&h[batch[n]], 1);
    __syncthreads();
    if (t < N_GRAPHS && h[t]) atomicAdd(&cnt[t], h[t]);
}

// ---- exclusive scan (3-kernel, block size 256)
__global__ void k_scan1(const int* __restrict__ deg, int* __restrict__ off,
                        int* __restrict__ bsums) {
    __shared__ int sm[256];
    int t = threadIdx.x;
    int i = blockIdx.x * 256 + t;
    int v = (i < N_NODES) ? deg[i] : 0;
    sm[t] = v;
    __syncthreads();
    for (int d = 1; d < 256; d <<= 1) {
        int add = (t >= d) ? sm[t - d] : 0;
        __syncthreads();
        sm[t] += add;
        __syncthreads();
    }
    if (i < N_NODES) off[i] = sm[t] - v;  // block-local exclusive
    if (t == 255) bsums[blockIdx.x] = sm[255];
}

__global__ void k_scan2(const int* __restrict__ bsums, int* __restrict__ bsumoff, int nb) {
    __shared__ int sm[512];
    int t = threadIdx.x;
    int v = (t < nb) ? bsums[t] : 0;
    sm[t] = v;
    __syncthreads();
    for (int d = 1; d < 512; d <<= 1) {
        int add = (t >= d) ? sm[t - d] : 0;
        __syncthreads();
        sm[t] += add;
        __syncthreads();
    }
    if (t < nb) bsumoff[t] = sm[t] - v;  // exclusive block offsets
}

__global__ void k_scan3(int* __restrict__ off, const int* __restrict__ bsumoff) {
    int i = blockIdx.x * blockDim.x + threadIdx.x;
    if (i < N_NODES) off[i] += bsumoff[i >> 8];
    if (i == 0) off[N_NODES] = N_EDGES;
}

// ---- CSR fill (src ids bucketed by dst)
__global__ void k_fill(const int* __restrict__ src, const int* __restrict__ dst,
                       const int* __restrict__ off, int* __restrict__ cursor,
                       int* __restrict__ csr) {
    int e = blockIdx.x * blockDim.x + threadIdx.x;
    if (e < N_EDGES) {
        int d = dst[e];
        int p = atomicAdd(&cursor[d], 1);
        csr[off[d] + p] = src[e];
    }
}

// ---- Layer 1: rank-1 GAT. One thread per destination node -> s1[n,h] = sum alpha * x[src]
__global__ void k_layer1(const float* __restrict__ x, const float* __restrict__ wsd,
                         const int* __restrict__ off, const int* __restrict__ csr,
                         float* __restrict__ s1) {
    int n = blockIdx.x * blockDim.x + threadIdx.x;
    if (n >= N_NODES) return;
    float xn = x[n];
    float ws[8], wd[8];
#pragma unroll
    for (int h = 0; h < 8; ++h) { ws[h] = wsd[h]; wd[h] = wsd[8 + h]; }
    float num[8], den[8];
#pragma unroll
    for (int h = 0; h < 8; ++h) {  // self loop (src = n)
        float w = __expf(lrelu(xn * ws[h] + xn * wd[h]));
        den[h] = w;
        num[h] = w * xn;
    }
    int b = off[n], e = off[n + 1];
    for (int i = b; i < e; ++i) {
        int s = csr[i];
        float xs = x[s];
#pragma unroll
        for (int h = 0; h < 8; ++h) {
            float w = __expf(lrelu(xs * ws[h] + xn * wd[h]));
            den[h] += w;
            num[h] += w * xs;
        }
    }
#pragma unroll
    for (int h = 0; h < 8; ++h) s1[n * 8 + h] = num[h] / den[h];
}

// ---- Fused: h1_act (ELU) regeneration + [N,64]@[64,128] GEMM + a_src2/a_dst2 epilogue.
// One wave per node; lane l owns output cols j=l and j=64+l.
__global__ __launch_bounds__(256) void k_gemm(
    const float* __restrict__ s1, const float* __restrict__ W1, const float* __restrict__ b1,
    const float* __restrict__ W2, const float* __restrict__ as2, const float* __restrict__ ad2,
    float* __restrict__ h2, float* __restrict__ asrc2, float* __restrict__ adst2) {
    __shared__ float smW2[64 * 128];
    int t = threadIdx.x;
    for (int idx = t; idx < 64 * 128; idx += 256) smW2[idx] = W2[idx];
    __syncthreads();
    int wid = t >> 6, l = t & 63;
    int n = blockIdx.x * 4 + wid;
    if (n >= N_NODES) return;

    // a[k] for k=l: h1_act[n,l] = elu(s1[n, l>>3] * W1[l] + b1[l])
    float a = elu_f(s1[n * 8 + (l >> 3)] * W1[l] + b1[l]);

    float acc0 = 0.f, acc1 = 0.f;
#pragma unroll
    for (int k = 0; k < 64; ++k) {
        float ak = __shfl(a, k, 64);
        acc0 += ak * smW2[k * 128 + l];
        acc1 += ak * smW2[k * 128 + 64 + l];
    }
    h2[n * 128 + l] = acc0;
    h2[n * 128 + 64 + l] = acc1;

    // a_src2[n,h] = sum_c h2[n,h*16+c]*att_src2[h,c]; flat att index for lane l is l (slot A), l+64 (slot B)
    float pSA = acc0 * as2[l];
    float pSB = acc1 * as2[64 + l];
    float pDA = acc0 * ad2[l];
    float pDB = acc1 * ad2[64 + l];
#pragma unroll
    for (int d = 1; d < 16; d <<= 1) {
        pSA += __shfl_xor(pSA, d, 64);
        pSB += __shfl_xor(pSB, d, 64);
        pDA += __shfl_xor(pDA, d, 64);
        pDB += __shfl_xor(pDB, d, 64);
    }
    if ((l & 15) == 0) {
        int h = l >> 4;
        asrc2[n * 8 + h]     = pSA;
        asrc2[n * 8 + 4 + h] = pSB;
        adst2[n * 8 + h]     = pDA;
        adst2[n * 8 + 4 + h] = pDB;
    }
}

// ---- Layer 2 aggregation + head-mean + pooled accumulation.
// One wave per destination node; lane l owns (h=l>>4, c=l&15) and (h+4, c).
// Pool path: combine the block's 4 waves in LDS first (batch sorted -> usually
// one graph per block), then 16 global atomics per distinct graph per block.
__global__ __launch_bounds__(256) void k_layer2(
    const float* __restrict__ h2, const float* __restrict__ asrc2,
    const float* __restrict__ adst2, const int* __restrict__ off,
    const int* __restrict__ csr, const int* __restrict__ batch,
    float* __restrict__ pool) {
    __shared__ float smv[4][16];
    __shared__ int smg[4];
    int t = threadIdx.x;
    int wid = t >> 6, l = t & 63;
    int n = blockIdx.x * 4 + wid;  // grid is exact: 25000*4 == N_NODES
    int hA = l >> 4;
    float adA = adst2[n * 8 + hA];
    float adB = adst2[n * 8 + 4 + hA];

    // self loop
    float wA = __expf(lrelu(asrc2[n * 8 + hA] + adA));
    float wB = __expf(lrelu(asrc2[n * 8 + 4 + hA] + adB));
    float accA = wA * h2[n * 128 + l];
    float accB = wB * h2[n * 128 + 64 + l];
    float denA = wA, denB = wB;

    int b = off[n], e = off[n + 1];
    for (int i = b; i < e; ++i) {
        int s = csr[i];
        float eA = __expf(lrelu(asrc2[s * 8 + hA] + adA));
        float eB = __expf(lrelu(asrc2[s * 8 + 4 + hA] + adB));
        accA += eA * h2[s * 128 + l];
        accB += eB * h2[s * 128 + 64 + l];
        denA += eA;
        denB += eB;
    }
    float v = accA / denA + accB / denB;  // two of the 8 heads for channel c
    v += __shfl_xor(v, 16, 64);
    v += __shfl_xor(v, 32, 64);
    v *= 0.125f;  // mean over 8 heads
    if (l < 16) smv[wid][l] = v;
    if (l == 0) smg[wid] = (int)batch[n];
    __syncthreads();
    if (t < 64) {
        int w = t >> 4, c = t & 15;
        int g = smg[w];
        bool leader = true;
        for (int w2 = 0; w2 < w; ++w2)
            if (smg[w2] == g) { leader = false; break; }
        if (leader) {
            float s = smv[w][c];
            for (int w2 = w + 1; w2 < 4; ++w2)
                if (smg[w2] == g) s += smv[w2][c];
            atomicAdd(&pool[g * 16 + c], s);
        }
    }
}

// ---- final: pooled mean (+b2) @ Wfc + bfc -> [64,4]
__global__ void k_final(const float* __restrict__ pool, const int* __restrict__ cnt,
                        const float* __restrict__ b2, const float* __restrict__ Wfc,
                        const float* __restrict__ bfc, float* __restrict__ out) {
    int t = threadIdx.x;
    int g = t >> 2, k = t & 3;
    float c = (float)(cnt[g] > 0 ? cnt[g] : 1);
    float acc = bfc[k];
#pragma unroll
    for (int ci = 0; ci < 16; ++ci)
        acc += (pool[g * 16 + ci] / c + b2[ci]) * Wfc[ci * 4 + k];
    out[g * 4 + k] = acc;
}

extern "C" void kernel_launch(void* const* d_in, const int* in_sizes, int n_in,
                              void* d_out, int out_size, void* d_ws, size_t ws_size,
                              hipStream_t stream) {
    const float* x   = (const float*)d_in[0];
    const float* W1  = (const float*)d_in[1];
    const float* as1 = (const float*)d_in[2];
    const float* ad1 = (const float*)d_in[3];
    const float* b1  = (const float*)d_in[4];
    const float* W2  = (const float*)d_in[5];
    const float* as2 = (const float*)d_in[6];
    const float* ad2 = (const float*)d_in[7];
    const float* b2  = (const float*)d_in[8];
    const float* Wfc = (const float*)d_in[9];
    const float* bfc = (const float*)d_in[10];
    const int* ei    = (const int*)d_in[11];
    const int* batch = (const int*)d_in[12];
    const int* srcv  = ei;             // edge_index[0]
    const int* dstv  = ei + N_EDGES;   // edge_index[1]

    char* ws = (char*)d_ws;
    size_t o = 0;
    auto alloc = [&](size_t bytes) {
        void* p = ws + o;
        o += (bytes + 255) & ~(size_t)255;
        return p;
    };
    // zero-region first (one memset): deg, cursor, cnt, pool
    int*   deg     = (int*)alloc((size_t)N_NODES * 4);
    int*   cursor  = (int*)alloc((size_t)N_NODES * 4);
    int*   cnt     = (int*)alloc(64 * 4);
    float* pool    = (float*)alloc(64 * 16 * 4);
    size_t zbytes  = o;
    int*   off     = (int*)alloc((size_t)(N_NODES + 1) * 4);
    int*   bsums   = (int*)alloc(512 * 4);
    int*   bsumoff = (int*)alloc(512 * 4);
    int*   csr     = (int*)alloc((size_t)N_EDGES * 4);
    float* s1      = (float*)alloc((size_t)N_NODES * 8 * 4);
    float* h2      = (float*)alloc((size_t)N_NODES * 128 * 4);
    float* asrc2   = (float*)alloc((size_t)N_NODES * 8 * 4);
    float* adst2   = (float*)alloc((size_t)N_NODES * 8 * 4);
    float* wsd     = (float*)alloc(16 * 4);

    hipMemsetAsync(d_ws, 0, zbytes, stream);

    int nbN = (N_NODES + 255) / 256;   // 391
    int nbE = (N_EDGES + 255) / 256;

    k_ws1<<<1, 64, 0, stream>>>(W1, as1, ad1, wsd);
    k_deg<<<nbE, 256, 0, stream>>>(dstv, deg);
    k_cnt<<<nbN, 256, 0, stream>>>(batch, cnt);
    k_scan1<<<nbN, 256, 0, stream>>>(deg, off, bsums);
    k_scan2<<<1, 512, 0, stream>>>(bsums, bsumoff, nbN);
    k_scan3<<<nbN, 256, 0, stream>>>(off, bsumoff);
    k_fill<<<nbE, 256, 0, stream>>>(srcv, dstv, off, cursor, csr);
    k_layer1<<<nbN, 256, 0, stream>>>(x, wsd, off, csr, s1);
    k_gemm<<<N_NODES / 4, 256, 0, stream>>>(s1, W1, b1, W2, as2, ad2, h2, asrc2, adst2);
    k_layer2<<<N_NODES / 4, 256, 0, stream>>>(h2, asrc2, adst2, off, csr, batch, pool);
    k_final<<<1, 256, 0, stream>>>(pool, cnt, b2, Wfc, bfc, (float*)d_out);
}

// Round 3
// 610.527 us; speedup vs baseline: 1.9381x; 1.0598x over previous
//
#include <hip/hip_runtime.h>
#include <hip/hip_fp16.h>

#define N_NODES  100000
#define N_EDGES  1600000
#define N_GRAPHS 64

__device__ __forceinline__ float lrelu(float v) { return v > 0.f ? v : 0.2f * v; }
__device__ __forceinline__ float elu_f(float v) { return v > 0.f ? v : __expf(v) - 1.f; }

// ---- merged: in-degree histogram (random dst, low contention) + graph-size
// histogram via LDS (batch sorted -> LDS pre-combine avoids serialized atomics)
__global__ void k_deg_cnt(const int* __restrict__ dst, int* __restrict__ deg,
                          const int* __restrict__ batch, int* __restrict__ cnt) {
    __shared__ int h[N_GRAPHS];
    int t = threadIdx.x;
    int gid = blockIdx.x * 256 + t;
    if (t < N_GRAPHS) h[t] = 0;
    __syncthreads();
    if (gid < N_EDGES) atomicAdd(&deg[dst[gid]], 1);
    if (gid < N_NODES) atomicAdd(&h[batch[gid]], 1);
    __syncthreads();
    if (t < N_GRAPHS && h[t]) atomicAdd(&cnt[t], h[t]);
}

// ---- exclusive scan (3-kernel, block size 256)
__global__ void k_scan1(const int* __restrict__ deg, int* __restrict__ off,
                        int* __restrict__ bsums) {
    __shared__ int sm[256];
    int t = threadIdx.x;
    int i = blockIdx.x * 256 + t;
    int v = (i < N_NODES) ? deg[i] : 0;
    sm[t] = v;
    __syncthreads();
    for (int d = 1; d < 256; d <<= 1) {
        int add = (t >= d) ? sm[t - d] : 0;
        __syncthreads();
        sm[t] += add;
        __syncthreads();
    }
    if (i < N_NODES) off[i] = sm[t] - v;  // block-local exclusive
    if (t == 255) bsums[blockIdx.x] = sm[255];
}

__global__ void k_scan2(const int* __restrict__ bsums, int* __restrict__ bsumoff, int nb) {
    __shared__ int sm[512];
    int t = threadIdx.x;
    int v = (t < nb) ? bsums[t] : 0;
    sm[t] = v;
    __syncthreads();
    for (int d = 1; d < 512; d <<= 1) {
        int add = (t >= d) ? sm[t - d] : 0;
        __syncthreads();
        sm[t] += add;
        __syncthreads();
    }
    if (t < nb) bsumoff[t] = sm[t] - v;  // exclusive block offsets
}

__global__ void k_scan3(int* __restrict__ off, const int* __restrict__ bsumoff) {
    int i = blockIdx.x * blockDim.x + threadIdx.x;
    if (i < N_NODES) off[i] += bsumoff[i >> 8];
    if (i == 0) off[N_NODES] = N_EDGES;
}

// ---- CSR fill (src ids bucketed by dst)
__global__ void k_fill(const int* __restrict__ src, const int* __restrict__ dst,
                       const int* __restrict__ off, int* __restrict__ cursor,
                       int* __restrict__ csr) {
    int e = blockIdx.x * blockDim.x + threadIdx.x;
    if (e < N_EDGES) {
        int d = dst[e];
        int p = atomicAdd(&cursor[d], 1);
        csr[off[d] + p] = src[e];
    }
}

// ---- Layer 1: rank-1 GAT. 16 lanes per destination node (4 nodes/wave).
// Lane c handles edges b+c, b+c+16, ...; shuffle-reduce 8 num/den pairs.
__global__ __launch_bounds__(256) void k_layer1(
    const float* __restrict__ x, const float* __restrict__ W1,
    const float* __restrict__ as1, const float* __restrict__ ad1,
    const int* __restrict__ off, const int* __restrict__ csr,
    float* __restrict__ s1) {
    __shared__ float smws[8], smwd[8];
    int t = threadIdx.x;
    if (t < 8) {  // fold the ws/wd precompute in (once per block)
        float s = 0.f, d = 0.f;
        for (int c = 0; c < 8; ++c) {
            float w = W1[t * 8 + c];
            s += w * as1[t * 8 + c];
            d += w * ad1[t * 8 + c];
        }
        smws[t] = s;
        smwd[t] = d;
    }
    __syncthreads();
    int n = blockIdx.x * 16 + (t >> 4);  // grid exact: 6250*16 == N_NODES
    int c = t & 15;
    float ws[8], wd[8];
#pragma unroll
    for (int h = 0; h < 8; ++h) { ws[h] = smws[h]; wd[h] = smwd[h]; }
    float xn = x[n];
    float num[8], den[8];
#pragma unroll
    for (int h = 0; h < 8; ++h) { num[h] = 0.f; den[h] = 0.f; }
    if (c == 0) {  // self loop
#pragma unroll
        for (int h = 0; h < 8; ++h) {
            float w = __expf(lrelu(xn * ws[h] + xn * wd[h]));
            den[h] = w;
            num[h] = w * xn;
        }
    }
    int b = off[n], e = off[n + 1];
    for (int i = b + c; i < e; i += 16) {
        int s = csr[i];
        float xs = x[s];
#pragma unroll
        for (int h = 0; h < 8; ++h) {
            float w = __expf(lrelu(xs * ws[h] + xn * wd[h]));
            den[h] += w;
            num[h] += w * xs;
        }
    }
#pragma unroll
    for (int d = 1; d < 16; d <<= 1) {
#pragma unroll
        for (int h = 0; h < 8; ++h) {
            num[h] += __shfl_xor(num[h], d, 64);
            den[h] += __shfl_xor(den[h], d, 64);
        }
    }
    if (c == 0) {
        float4 v0 = make_float4(num[0] / den[0], num[1] / den[1], num[2] / den[2], num[3] / den[3]);
        float4 v1 = make_float4(num[4] / den[4], num[5] / den[5], num[6] / den[6], num[7] / den[7]);
        *(float4*)&s1[n * 8]     = v0;
        *(float4*)&s1[n * 8 + 4] = v1;
    }
}

// ---- Fused: h1_act (ELU) regeneration + [N,64]@[64,128] GEMM + attention epilogue.
// One wave per node; lane l owns output cols j=l and j=64+l.
// Outputs: h2p half2-packed {col l, col 64+l}; ap/dp float2 {head h, head h+4}.
__global__ __launch_bounds__(256) void k_gemm(
    const float* __restrict__ s1, const float* __restrict__ W1, const float* __restrict__ b1,
    const float* __restrict__ W2, const float* __restrict__ as2, const float* __restrict__ ad2,
    __half2* __restrict__ h2p, float2* __restrict__ ap, float2* __restrict__ dp) {
    __shared__ float smW2[64 * 128];
    int t = threadIdx.x;
    for (int idx = t; idx < 64 * 128; idx += 256) smW2[idx] = W2[idx];
    __syncthreads();
    int wid = t >> 6, l = t & 63;
    int n = blockIdx.x * 4 + wid;  // grid exact: 25000*4 == N_NODES

    // a[k] for k=l: h1_act[n,l] = elu(s1[n, l>>3] * W1[l] + b1[l])
    float a = elu_f(s1[n * 8 + (l >> 3)] * W1[l] + b1[l]);

    float acc0 = 0.f, acc1 = 0.f;
#pragma unroll
    for (int k = 0; k < 64; ++k) {
        float ak = __shfl(a, k, 64);
        acc0 += ak * smW2[k * 128 + l];
        acc1 += ak * smW2[k * 128 + 64 + l];
    }
    h2p[n * 64 + l] = __floats2half2_rn(acc0, acc1);

    // a_src2[n,h] = sum_c h2[n,h*16+c]*att_src2[h,c]; flat att index for lane l is l / l+64
    float pSA = acc0 * as2[l];
    float pSB = acc1 * as2[64 + l];
    float pDA = acc0 * ad2[l];
    float pDB = acc1 * ad2[64 + l];
#pragma unroll
    for (int d = 1; d < 16; d <<= 1) {
        pSA += __shfl_xor(pSA, d, 64);
        pSB += __shfl_xor(pSB, d, 64);
        pDA += __shfl_xor(pDA, d, 64);
        pDB += __shfl_xor(pDB, d, 64);
    }
    if ((l & 15) == 0) {
        int h = l >> 4;
        ap[n * 4 + h] = make_float2(pSA, pSB);
        dp[n * 4 + h] = make_float2(pDA, pDB);
    }
}

// ---- Layer 2 aggregation + head-mean + pooled accumulation.
// One wave per destination node; lane l owns (h=l>>4, c=l&15) and (h+4, c).
// Per edge: one 4B half2 load (256B/wave) + one 8B float2 load -> ~half the fetch.
__global__ __launch_bounds__(256) void k_layer2(
    const __half2* __restrict__ h2p, const float2* __restrict__ ap,
    const float2* __restrict__ dp, const int* __restrict__ off,
    const int* __restrict__ csr, const int* __restrict__ batch,
    float* __restrict__ pool) {
    __shared__ float smv[4][16];
    __shared__ int smg[4];
    int t = threadIdx.x;
    int wid = t >> 6, l = t & 63;
    int n = blockIdx.x * 4 + wid;  // grid exact
    int hA = l >> 4;
    float2 ad = dp[n * 4 + hA];

    // self loop
    float2 an = ap[n * 4 + hA];
    float wA = __expf(lrelu(an.x + ad.x));
    float wB = __expf(lrelu(an.y + ad.y));
    float2 hn = __half22float2(h2p[n * 64 + l]);
    float accA = wA * hn.x;
    float accB = wB * hn.y;
    float denA = wA, denB = wB;

    int b = off[n], e = off[n + 1];
    for (int i = b; i < e; ++i) {
        int s = csr[i];
        float2 as = ap[s * 4 + hA];
        float2 hs = __half22float2(h2p[s * 64 + l]);
        float eA = __expf(lrelu(as.x + ad.x));
        float eB = __expf(lrelu(as.y + ad.y));
        accA += eA * hs.x;
        accB += eB * hs.y;
        denA += eA;
        denB += eB;
    }
    float v = accA / denA + accB / denB;  // two of the 8 heads for channel c
    v += __shfl_xor(v, 16, 64);
    v += __shfl_xor(v, 32, 64);
    v *= 0.125f;  // mean over 8 heads
    if (l < 16) smv[wid][l] = v;
    if (l == 0) smg[wid] = batch[n];
    __syncthreads();
    if (t < 64) {
        int w = t >> 4, c = t & 15;
        int g = smg[w];
        bool leader = true;
        for (int w2 = 0; w2 < w; ++w2)
            if (smg[w2] == g) { leader = false; break; }
        if (leader) {
            float s = smv[w][c];
            for (int w2 = w + 1; w2 < 4; ++w2)
                if (smg[w2] == g) s += smv[w2][c];
            atomicAdd(&pool[g * 16 + c], s);
        }
    }
}

// ---- final: pooled mean (+b2) @ Wfc + bfc -> [64,4]
__global__ void k_final(const float* __restrict__ pool, const int* __restrict__ cnt,
                        const float* __restrict__ b2, const float* __restrict__ Wfc,
                        const float* __restrict__ bfc, float* __restrict__ out) {
    int t = threadIdx.x;
    int g = t >> 2, k = t & 3;
    float c = (float)(cnt[g] > 0 ? cnt[g] : 1);
    float acc = bfc[k];
#pragma unroll
    for (int ci = 0; ci < 16; ++ci)
        acc += (pool[g * 16 + ci] / c + b2[ci]) * Wfc[ci * 4 + k];
    out[g * 4 + k] = acc;
}

extern "C" void kernel_launch(void* const* d_in, const int* in_sizes, int n_in,
                              void* d_out, int out_size, void* d_ws, size_t ws_size,
                              hipStream_t stream) {
    const float* x   = (const float*)d_in[0];
    const float* W1  = (const float*)d_in[1];
    const float* as1 = (const float*)d_in[2];
    const float* ad1 = (const float*)d_in[3];
    const float* b1  = (const float*)d_in[4];
    const float* W2  = (const float*)d_in[5];
    const float* as2 = (const float*)d_in[6];
    const float* ad2 = (const float*)d_in[7];
    const float* b2  = (const float*)d_in[8];
    const float* Wfc = (const float*)d_in[9];
    const float* bfc = (const float*)d_in[10];
    const int* ei    = (const int*)d_in[11];
    const int* batch = (const int*)d_in[12];
    const int* srcv  = ei;             // edge_index[0]
    const int* dstv  = ei + N_EDGES;   // edge_index[1]

    char* ws = (char*)d_ws;
    size_t o = 0;
    auto alloc = [&](size_t bytes) {
        void* p = ws + o;
        o += (bytes + 255) & ~(size_t)255;
        return p;
    };
    // zero-region first (one memset): deg, cursor, cnt, pool
    int*    deg     = (int*)alloc((size_t)N_NODES * 4);
    int*    cursor  = (int*)alloc((size_t)N_NODES * 4);
    int*    cnt     = (int*)alloc(64 * 4);
    float*  pool    = (float*)alloc(64 * 16 * 4);
    size_t  zbytes  = o;
    int*    off     = (int*)alloc((size_t)(N_NODES + 1) * 4);
    int*    bsums   = (int*)alloc(512 * 4);
    int*    bsumoff = (int*)alloc(512 * 4);
    int*    csr     = (int*)alloc((size_t)N_EDGES * 4);
    float*  s1      = (float*)alloc((size_t)N_NODES * 8 * 4);
    __half2* h2p    = (__half2*)alloc((size_t)N_NODES * 64 * 4);
    float2* ap      = (float2*)alloc((size_t)N_NODES * 4 * 8);
    float2* dp      = (float2*)alloc((size_t)N_NODES * 4 * 8);

    hipMemsetAsync(d_ws, 0, zbytes, stream);

    int nbN = (N_NODES + 255) / 256;   // 391
    int nbE = (N_EDGES + 255) / 256;   // 6250

    k_deg_cnt<<<nbE, 256, 0, stream>>>(dstv, deg, batch, cnt);
    k_scan1<<<nbN, 256, 0, stream>>>(deg, off, bsums);
    k_scan2<<<1, 512, 0, stream>>>(bsums, bsumoff, nbN);
    k_scan3<<<nbN, 256, 0, stream>>>(off, bsumoff);
    k_fill<<<nbE, 256, 0, stream>>>(srcv, dstv, off, cursor, csr);
    k_layer1<<<N_NODES / 16, 256, 0, stream>>>(x, W1, as1, ad1, off, csr, s1);
    k_gemm<<<N_NODES / 4, 256, 0, stream>>>(s1, W1, b1, W2, as2, ad2, h2p, ap, dp);
    k_layer2<<<N_NODES / 4, 256, 0, stream>>>(h2p, ap, dp, off, csr, batch, pool);
    k_final<<<1, 256, 0, stream>>>(pool, cnt, b2, Wfc, bfc, (float*)d_out);
}

// Round 4
// 511.215 us; speedup vs baseline: 2.3146x; 1.1943x over previous
//
#include <hip/hip_runtime.h>
#include <hip/hip_fp16.h>

#define N_NODES  100000
#define N_EDGES  1600000
#define N_GRAPHS 64

__device__ __forceinline__ float lrelu(float v) { return v > 0.f ? v : 0.2f * v; }
__device__ __forceinline__ float elu_f(float v) { return v > 0.f ? v : __expf(v) - 1.f; }

// ---- merged: in-degree histogram (random dst, low contention) + graph-size
// histogram via LDS (batch sorted -> LDS pre-combine avoids serialized atomics)
__global__ void k_deg_cnt(const int* __restrict__ dst, int* __restrict__ deg,
                          const int* __restrict__ batch, int* __restrict__ cnt) {
    __shared__ int h[N_GRAPHS];
    int t = threadIdx.x;
    int gid = blockIdx.x * 256 + t;
    if (t < N_GRAPHS) h[t] = 0;
    __syncthreads();
    if (gid < N_EDGES) atomicAdd(&deg[dst[gid]], 1);
    if (gid < N_NODES) atomicAdd(&h[batch[gid]], 1);
    __syncthreads();
    if (t < N_GRAPHS && h[t]) atomicAdd(&cnt[t], h[t]);
}

// ---- exclusive scan (3-kernel, block size 256)
__global__ void k_scan1(const int* __restrict__ deg, int* __restrict__ off,
                        int* __restrict__ bsums) {
    __shared__ int sm[256];
    int t = threadIdx.x;
    int i = blockIdx.x * 256 + t;
    int v = (i < N_NODES) ? deg[i] : 0;
    sm[t] = v;
    __syncthreads();
    for (int d = 1; d < 256; d <<= 1) {
        int add = (t >= d) ? sm[t - d] : 0;
        __syncthreads();
        sm[t] += add;
        __syncthreads();
    }
    if (i < N_NODES) off[i] = sm[t] - v;  // block-local exclusive
    if (t == 255) bsums[blockIdx.x] = sm[255];
}

__global__ void k_scan2(const int* __restrict__ bsums, int* __restrict__ bsumoff, int nb) {
    __shared__ int sm[512];
    int t = threadIdx.x;
    int v = (t < nb) ? bsums[t] : 0;
    sm[t] = v;
    __syncthreads();
    for (int d = 1; d < 512; d <<= 1) {
        int add = (t >= d) ? sm[t - d] : 0;
        __syncthreads();
        sm[t] += add;
        __syncthreads();
    }
    if (t < nb) bsumoff[t] = sm[t] - v;  // exclusive block offsets
}

// also seeds cursor with the final offsets so k_fill's atomic return IS the slot
__global__ void k_scan3(int* __restrict__ off, const int* __restrict__ bsumoff,
                        int* __restrict__ cursor) {
    int i = blockIdx.x * blockDim.x + threadIdx.x;
    if (i < N_NODES) {
        int v = off[i] + bsumoff[i >> 8];
        off[i] = v;
        cursor[i] = v;
    }
    if (i == 0) off[N_NODES] = N_EDGES;
}

// ---- CSR fill: atomic returns absolute slot (no random off[] read)
__global__ void k_fill(const int* __restrict__ src, const int* __restrict__ dst,
                       int* __restrict__ cursor, int* __restrict__ csr) {
    int e = blockIdx.x * blockDim.x + threadIdx.x;
    if (e < N_EDGES) {
        int p = atomicAdd(&cursor[dst[e]], 1);
        csr[p] = src[e];
    }
}

// ---- Layer 1: rank-1 GAT. 16 lanes per destination node (4 nodes/wave).
__global__ __launch_bounds__(256) void k_layer1(
    const float* __restrict__ x, const float* __restrict__ W1,
    const float* __restrict__ as1, const float* __restrict__ ad1,
    const int* __restrict__ off, const int* __restrict__ csr,
    float* __restrict__ s1) {
    __shared__ float smws[8], smwd[8];
    int t = threadIdx.x;
    if (t < 8) {  // fold the ws/wd precompute in (once per block)
        float s = 0.f, d = 0.f;
        for (int c = 0; c < 8; ++c) {
            float w = W1[t * 8 + c];
            s += w * as1[t * 8 + c];
            d += w * ad1[t * 8 + c];
        }
        smws[t] = s;
        smwd[t] = d;
    }
    __syncthreads();
    int n = blockIdx.x * 16 + (t >> 4);  // grid exact: 6250*16 == N_NODES
    int c = t & 15;
    float ws[8], wd[8];
#pragma unroll
    for (int h = 0; h < 8; ++h) { ws[h] = smws[h]; wd[h] = smwd[h]; }
    float xn = x[n];
    float num[8], den[8];
#pragma unroll
    for (int h = 0; h < 8; ++h) { num[h] = 0.f; den[h] = 0.f; }
    if (c == 0) {  // self loop
#pragma unroll
        for (int h = 0; h < 8; ++h) {
            float w = __expf(lrelu(xn * ws[h] + xn * wd[h]));
            den[h] = w;
            num[h] = w * xn;
        }
    }
    int b = off[n], e = off[n + 1];
    for (int i = b + c; i < e; i += 16) {
        int s = csr[i];
        float xs = x[s];
#pragma unroll
        for (int h = 0; h < 8; ++h) {
            float w = __expf(lrelu(xs * ws[h] + xn * wd[h]));
            den[h] += w;
            num[h] += w * xs;
        }
    }
#pragma unroll
    for (int d = 1; d < 16; d <<= 1) {
#pragma unroll
        for (int h = 0; h < 8; ++h) {
            num[h] += __shfl_xor(num[h], d, 64);
            den[h] += __shfl_xor(den[h], d, 64);
        }
    }
    if (c == 0) {
        float4 v0 = make_float4(num[0] / den[0], num[1] / den[1], num[2] / den[2], num[3] / den[3]);
        float4 v1 = make_float4(num[4] / den[4], num[5] / den[5], num[6] / den[6], num[7] / den[7]);
        *(float4*)&s1[n * 8]     = v0;
        *(float4*)&s1[n * 8 + 4] = v1;
    }
}

// ---- Fused: h1_act (ELU) + [N,64]@[64,128] GEMM + attention epilogue.
// One wave per node; lane l owns output cols j=l and j=64+l.
// a-row staged in LDS, read back as broadcast float4 (replaces 64 shfls).
__global__ __launch_bounds__(256) void k_gemm(
    const float* __restrict__ s1, const float* __restrict__ W1, const float* __restrict__ b1,
    const float* __restrict__ W2, const float* __restrict__ as2, const float* __restrict__ ad2,
    __half2* __restrict__ h2p, float2* __restrict__ ap, float2* __restrict__ dp) {
    __shared__ float smW2[64 * 128];
    __shared__ float smA[4][64];
    int t = threadIdx.x;
    for (int idx = t; idx < 64 * 128; idx += 256) smW2[idx] = W2[idx];
    int wid = t >> 6, l = t & 63;
    int n = blockIdx.x * 4 + wid;  // grid exact: 25000*4 == N_NODES

    // a[k] for k=l: h1_act[n,l] = elu(s1[n, l>>3] * W1[l] + b1[l])
    smA[wid][l] = elu_f(s1[n * 8 + (l >> 3)] * W1[l] + b1[l]);
    __syncthreads();

    float acc0 = 0.f, acc1 = 0.f;
    const float4* a4 = (const float4*)smA[wid];
#pragma unroll
    for (int kb = 0; kb < 16; ++kb) {
        float4 av = a4[kb];  // broadcast read: all lanes same address
        float ak[4] = {av.x, av.y, av.z, av.w};
#pragma unroll
        for (int u = 0; u < 4; ++u) {
            int k = kb * 4 + u;
            acc0 += ak[u] * smW2[k * 128 + l];
            acc1 += ak[u] * smW2[k * 128 + 64 + l];
        }
    }
    h2p[n * 64 + l] = __floats2half2_rn(acc0, acc1);

    // attention partials; flat att index for lane l is l / l+64
    float pSA = acc0 * as2[l];
    float pSB = acc1 * as2[64 + l];
    float pDA = acc0 * ad2[l];
    float pDB = acc1 * ad2[64 + l];
#pragma unroll
    for (int d = 1; d < 16; d <<= 1) {
        pSA += __shfl_xor(pSA, d, 64);
        pSB += __shfl_xor(pSB, d, 64);
        pDA += __shfl_xor(pDA, d, 64);
        pDB += __shfl_xor(pDB, d, 64);
    }
    if ((l & 15) == 0) {
        int h = l >> 4;
        ap[n * 4 + h] = make_float2(pSA, pSB);
        dp[n * 4 + h] = make_float2(pDA, pDB);
    }
}

// ---- Layer 2 aggregation + head-mean + pooled accumulation.
// One wave per destination node; lane l owns (h=l>>4, c=l&15) and (h+4, c).
// MLP restructure: one coalesced csr load per <=64-edge chunk, then a 4-way
// unrolled loop of INDEPENDENT gather chains (src ids broadcast via shfl).
__global__ __launch_bounds__(256) void k_layer2(
    const __half2* __restrict__ h2p, const float2* __restrict__ ap,
    const float2* __restrict__ dp, const int* __restrict__ off,
    const int* __restrict__ csr, const int* __restrict__ batch,
    float* __restrict__ pool) {
    __shared__ float smv[4][16];
    __shared__ int smg[4];
    int t = threadIdx.x;
    int wid = t >> 6, l = t & 63;
    int n = blockIdx.x * 4 + wid;  // grid exact
    int hA = l >> 4;
    float2 ad = dp[n * 4 + hA];

    // self loop
    float2 an = ap[n * 4 + hA];
    float wA = __expf(lrelu(an.x + ad.x));
    float wB = __expf(lrelu(an.y + ad.y));
    float2 hn = __half22float2(h2p[n * 64 + l]);
    float accA = wA * hn.x;
    float accB = wB * hn.y;
    float denA = wA, denB = wB;

    int b = off[n];
    int deg = off[n + 1] - b;
    for (int base = 0; base < deg; base += 64) {
        int rem = deg - base;
        if (rem > 64) rem = 64;
        int sl = (l < rem) ? csr[b + base + l] : 0;  // one coalesced load / chunk
        int j = 0;
        for (; j + 4 <= rem; j += 4) {
            int s0 = __shfl(sl, j, 64);
            int s1i = __shfl(sl, j + 1, 64);
            int s2i = __shfl(sl, j + 2, 64);
            int s3i = __shfl(sl, j + 3, 64);
            float2 p0 = ap[s0 * 4 + hA];
            float2 p1 = ap[s1i * 4 + hA];
            float2 p2 = ap[s2i * 4 + hA];
            float2 p3 = ap[s3i * 4 + hA];
            float2 g0 = __half22float2(h2p[s0 * 64 + l]);
            float2 g1 = __half22float2(h2p[s1i * 64 + l]);
            float2 g2 = __half22float2(h2p[s2i * 64 + l]);
            float2 g3 = __half22float2(h2p[s3i * 64 + l]);
            float e0 = __expf(lrelu(p0.x + ad.x)), f0 = __expf(lrelu(p0.y + ad.y));
            float e1 = __expf(lrelu(p1.x + ad.x)), f1 = __expf(lrelu(p1.y + ad.y));
            float e2 = __expf(lrelu(p2.x + ad.x)), f2 = __expf(lrelu(p2.y + ad.y));
            float e3 = __expf(lrelu(p3.x + ad.x)), f3 = __expf(lrelu(p3.y + ad.y));
            accA += e0 * g0.x; accB += f0 * g0.y;
            accA += e1 * g1.x; accB += f1 * g1.y;
            accA += e2 * g2.x; accB += f2 * g2.y;
            accA += e3 * g3.x; accB += f3 * g3.y;
            denA += (e0 + e1) + (e2 + e3);
            denB += (f0 + f1) + (f2 + f3);
        }
        for (; j < rem; ++j) {
            int s = __shfl(sl, j, 64);
            float2 p = ap[s * 4 + hA];
            float2 g = __half22float2(h2p[s * 64 + l]);
            float eA = __expf(lrelu(p.x + ad.x));
            float eB = __expf(lrelu(p.y + ad.y));
            accA += eA * g.x; accB += eB * g.y;
            denA += eA; denB += eB;
        }
    }
    float v = accA / denA + accB / denB;  // two of the 8 heads for channel c
    v += __shfl_xor(v, 16, 64);
    v += __shfl_xor(v, 32, 64);
    v *= 0.125f;  // mean over 8 heads
    if (l < 16) smv[wid][l] = v;
    if (l == 0) smg[wid] = batch[n];
    __syncthreads();
    if (t < 64) {
        int w = t >> 4, c = t & 15;
        int g = smg[w];
        bool leader = true;
        for (int w2 = 0; w2 < w; ++w2)
            if (smg[w2] == g) { leader = false; break; }
        if (leader) {
            float s = smv[w][c];
            for (int w2 = w + 1; w2 < 4; ++w2)
                if (smg[w2] == g) s += smv[w2][c];
            atomicAdd(&pool[g * 16 + c], s);
        }
    }
}

// ---- final: pooled mean (+b2) @ Wfc + bfc -> [64,4]
__global__ void k_final(const float* __restrict__ pool, const int* __restrict__ cnt,
                        const float* __restrict__ b2, const float* __restrict__ Wfc,
                        const float* __restrict__ bfc, float* __restrict__ out) {
    int t = threadIdx.x;
    int g = t >> 2, k = t & 3;
    float c = (float)(cnt[g] > 0 ? cnt[g] : 1);
    float acc = bfc[k];
#pragma unroll
    for (int ci = 0; ci < 16; ++ci)
        acc += (pool[g * 16 + ci] / c + b2[ci]) * Wfc[ci * 4 + k];
    out[g * 4 + k] = acc;
}

extern "C" void kernel_launch(void* const* d_in, const int* in_sizes, int n_in,
                              void* d_out, int out_size, void* d_ws, size_t ws_size,
                              hipStream_t stream) {
    const float* x   = (const float*)d_in[0];
    const float* W1  = (const float*)d_in[1];
    const float* as1 = (const float*)d_in[2];
    const float* ad1 = (const float*)d_in[3];
    const float* b1  = (const float*)d_in[4];
    const float* W2  = (const float*)d_in[5];
    const float* as2 = (const float*)d_in[6];
    const float* ad2 = (const float*)d_in[7];
    const float* b2  = (const float*)d_in[8];
    const float* Wfc = (const float*)d_in[9];
    const float* bfc = (const float*)d_in[10];
    const int* ei    = (const int*)d_in[11];
    const int* batch = (const int*)d_in[12];
    const int* srcv  = ei;             // edge_index[0]
    const int* dstv  = ei + N_EDGES;   // edge_index[1]

    char* ws = (char*)d_ws;
    size_t o = 0;
    auto alloc = [&](size_t bytes) {
        void* p = ws + o;
        o += (bytes + 255) & ~(size_t)255;
        return p;
    };
    // zero-region first (one memset): deg, cnt, pool
    int*    deg     = (int*)alloc((size_t)N_NODES * 4);
    int*    cnt     = (int*)alloc(64 * 4);
    float*  pool    = (float*)alloc(64 * 16 * 4);
    size_t  zbytes  = o;
    int*    cursor  = (int*)alloc((size_t)N_NODES * 4);   // seeded by k_scan3
    int*    off     = (int*)alloc((size_t)(N_NODES + 1) * 4);
    int*    bsums   = (int*)alloc(512 * 4);
    int*    bsumoff = (int*)alloc(512 * 4);
    int*    csr     = (int*)alloc((size_t)N_EDGES * 4);
    float*  s1      = (float*)alloc((size_t)N_NODES * 8 * 4);
    __half2* h2p    = (__half2*)alloc((size_t)N_NODES * 64 * 4);
    float2* ap      = (float2*)alloc((size_t)N_NODES * 4 * 8);
    float2* dp      = (float2*)alloc((size_t)N_NODES * 4 * 8);

    hipMemsetAsync(d_ws, 0, zbytes, stream);

    int nbN = (N_NODES + 255) / 256;   // 391
    int nbE = (N_EDGES + 255) / 256;   // 6250

    k_deg_cnt<<<nbE, 256, 0, stream>>>(dstv, deg, batch, cnt);
    k_scan1<<<nbN, 256, 0, stream>>>(deg, off, bsums);
    k_scan2<<<1, 512, 0, stream>>>(bsums, bsumoff, nbN);
    k_scan3<<<nbN, 256, 0, stream>>>(off, bsumoff, cursor);
    k_fill<<<nbE, 256, 0, stream>>>(srcv, dstv, cursor, csr);
    k_layer1<<<N_NODES / 16, 256, 0, stream>>>(x, W1, as1, ad1, off, csr, s1);
    k_gemm<<<N_NODES / 4, 256, 0, stream>>>(s1, W1, b1, W2, as2, ad2, h2p, ap, dp);
    k_layer2<<<N_NODES / 4, 256, 0, stream>>>(h2p, ap, dp, off, csr, batch, pool);
    k_final<<<1, 256, 0, stream>>>(pool, cnt, b2, Wfc, bfc, (float*)d_out);
}

// Round 5
// 347.243 us; speedup vs baseline: 3.4076x; 1.4722x over previous
//
#include <hip/hip_runtime.h>
#include <hip/hip_fp16.h>

#define N_NODES  100000
#define N_EDGES  1600000
#define N_GRAPHS 64

#define BINSH  9
#define NBIN   196          // ceil(100000 / 512)
#define BINCAP 16384        // Poisson(8163) max ~8.6K; 2x headroom
#define EPB    4096         // edges per block in k_binA

__device__ __forceinline__ float lrelu(float v) { return v > 0.f ? v : 0.2f * v; }
__device__ __forceinline__ float elu_f(float v) { return v > 0.f ? v : __expf(v) - 1.f; }

// ---- Pass A: coarse-bin edges (dst>>9) into per-bin regions, coalesced runs.
// Also folds in the graph-size histogram over nodes.
__global__ __launch_bounds__(256) void k_binA(
    const int* __restrict__ src, const int* __restrict__ dst,
    const int* __restrict__ batch, int* __restrict__ gbin_cursor,
    int* __restrict__ cnt, int2* __restrict__ binned) {
    __shared__ int hist[NBIN], lexcl[NBIN], runbase[NBIN], lcur[NBIN];
    __shared__ int scan[256];
    __shared__ int gh[N_GRAPHS];
    __shared__ int2 stage[EPB];
    int t = threadIdx.x;
    int e0 = blockIdx.x * EPB;
    for (int b = t; b < NBIN; b += 256) hist[b] = 0;
    if (t < N_GRAPHS) gh[t] = 0;
    __syncthreads();
    // batch histogram (each block covers 256 nodes; 391*256 >= N_NODES)
    int nid = blockIdx.x * 256 + t;
    if (nid < N_NODES) atomicAdd(&gh[batch[nid]], 1);
    // step 1: bin histogram
    for (int i = t; i < EPB; i += 256) {
        int e = e0 + i;
        if (e < N_EDGES) atomicAdd(&hist[dst[e] >> BINSH], 1);
    }
    __syncthreads();
    // step 2: exclusive scan of hist (Hillis-Steele over 256 slots)
    int v = (t < NBIN) ? hist[t] : 0;
    scan[t] = v;
    __syncthreads();
    for (int d = 1; d < 256; d <<= 1) {
        int a = (t >= d) ? scan[t - d] : 0;
        __syncthreads();
        scan[t] += a;
        __syncthreads();
    }
    if (t < NBIN) { lexcl[t] = scan[t] - v; lcur[t] = scan[t] - v; }
    __syncthreads();
    if (t < NBIN && hist[t] > 0) runbase[t] = atomicAdd(&gbin_cursor[t], hist[t]);
    if (t < N_GRAPHS && gh[t]) atomicAdd(&cnt[t], gh[t]);
    __syncthreads();
    // step 3: reorder into LDS staging (grouped by bin)
    for (int i = t; i < EPB; i += 256) {
        int e = e0 + i;
        if (e < N_EDGES) {
            int d = dst[e];
            int b = d >> BINSH;
            int p = atomicAdd(&lcur[b], 1);
            stage[p] = make_int2(src[e], d);
        }
    }
    __syncthreads();
    // step 4: coalesced run writes into fixed-capacity bin regions
    int m = N_EDGES - e0;
    if (m > EPB) m = EPB;
    for (int i = t; i < m; i += 256) {
        int2 pr = stage[i];
        int b = pr.y >> BINSH;
        binned[(size_t)b * BINCAP + runbase[b] + (i - lexcl[b])] = pr;
    }
}

// ---- tiny scan of bin counts -> compact csr bases
__global__ void k_binscan(const int* __restrict__ gbin_cursor, int* __restrict__ bin_base) {
    __shared__ int sm[256];
    int t = threadIdx.x;
    int v = (t < NBIN) ? gbin_cursor[t] : 0;
    sm[t] = v;
    __syncthreads();
    for (int d = 1; d < 256; d <<= 1) {
        int a = (t >= d) ? sm[t - d] : 0;
        __syncthreads();
        sm[t] += a;
        __syncthreads();
    }
    if (t < NBIN) bin_base[t] = sm[t] - v;
    if (t == 0) bin_base[NBIN] = N_EDGES;
}

// ---- Pass B: per-bin counting sort over 512 local nodes -> off[] + csr[].
// All csr writes land in a 32KB window per block (one L2, no line bouncing).
__global__ __launch_bounds__(1024) void k_binB(
    const int2* __restrict__ binned, const int* __restrict__ gbin_cursor,
    const int* __restrict__ bin_base, int* __restrict__ off, int* __restrict__ csr) {
    __shared__ int hist[512], sc[512];
    int b = blockIdx.x, t = threadIdx.x;
    int count = gbin_cursor[b];
    int ebase = bin_base[b];
    int node0 = b << BINSH;
    const int2* my = binned + (size_t)b * BINCAP;
    if (t < 512) hist[t] = 0;
    __syncthreads();
    for (int i = t; i < count; i += 1024) atomicAdd(&hist[my[i].y - node0], 1);
    __syncthreads();
    int v = (t < 512) ? hist[t] : 0;
    if (t < 512) sc[t] = v;
    __syncthreads();
    for (int d = 1; d < 512; d <<= 1) {
        int a = (t < 512 && t >= d) ? sc[t - d] : 0;
        __syncthreads();
        if (t < 512) sc[t] += a;
        __syncthreads();
    }
    if (t < 512) {
        int n = node0 + t;
        if (n < N_NODES) off[n] = ebase + sc[t] - v;
        hist[t] = sc[t] - v;  // becomes the local cursor
    }
    if (b == 0 && t == 0) off[N_NODES] = N_EDGES;
    __syncthreads();
    for (int i = t; i < count; i += 1024) {
        int2 pr = my[i];
        int p = atomicAdd(&hist[pr.y - node0], 1);
        csr[ebase + p] = pr.x;
    }
}

// ---- Layer 1: rank-1 GAT. 16 lanes per destination node (4 nodes/wave).
__global__ __launch_bounds__(256) void k_layer1(
    const float* __restrict__ x, const float* __restrict__ W1,
    const float* __restrict__ as1, const float* __restrict__ ad1,
    const int* __restrict__ off, const int* __restrict__ csr,
    float* __restrict__ s1) {
    __shared__ float smws[8], smwd[8];
    int t = threadIdx.x;
    if (t < 8) {  // fold the ws/wd precompute in (once per block)
        float s = 0.f, d = 0.f;
        for (int c = 0; c < 8; ++c) {
            float w = W1[t * 8 + c];
            s += w * as1[t * 8 + c];
            d += w * ad1[t * 8 + c];
        }
        smws[t] = s;
        smwd[t] = d;
    }
    __syncthreads();
    int n = blockIdx.x * 16 + (t >> 4);  // grid exact: 6250*16 == N_NODES
    int c = t & 15;
    float ws[8], wd[8];
#pragma unroll
    for (int h = 0; h < 8; ++h) { ws[h] = smws[h]; wd[h] = smwd[h]; }
    float xn = x[n];
    float num[8], den[8];
#pragma unroll
    for (int h = 0; h < 8; ++h) { num[h] = 0.f; den[h] = 0.f; }
    if (c == 0) {  // self loop
#pragma unroll
        for (int h = 0; h < 8; ++h) {
            float w = __expf(lrelu(xn * ws[h] + xn * wd[h]));
            den[h] = w;
            num[h] = w * xn;
        }
    }
    int b = off[n], e = off[n + 1];
    for (int i = b + c; i < e; i += 16) {
        int s = csr[i];
        float xs = x[s];
#pragma unroll
        for (int h = 0; h < 8; ++h) {
            float w = __expf(lrelu(xs * ws[h] + xn * wd[h]));
            den[h] += w;
            num[h] += w * xs;
        }
    }
#pragma unroll
    for (int d = 1; d < 16; d <<= 1) {
#pragma unroll
        for (int h = 0; h < 8; ++h) {
            num[h] += __shfl_xor(num[h], d, 64);
            den[h] += __shfl_xor(den[h], d, 64);
        }
    }
    if (c == 0) {
        float4 v0 = make_float4(num[0] / den[0], num[1] / den[1], num[2] / den[2], num[3] / den[3]);
        float4 v1 = make_float4(num[4] / den[4], num[5] / den[5], num[6] / den[6], num[7] / den[7]);
        *(float4*)&s1[n * 8]     = v0;
        *(float4*)&s1[n * 8 + 4] = v1;
    }
}

// ---- Fused: h1_act (ELU) + [N,64]@[64,128] GEMM + attention epilogue.
__global__ __launch_bounds__(256) void k_gemm(
    const float* __restrict__ s1, const float* __restrict__ W1, const float* __restrict__ b1,
    const float* __restrict__ W2, const float* __restrict__ as2, const float* __restrict__ ad2,
    __half2* __restrict__ h2p, float2* __restrict__ ap, float2* __restrict__ dp) {
    __shared__ float smW2[64 * 128];
    __shared__ float smA[4][64];
    int t = threadIdx.x;
    for (int idx = t; idx < 64 * 128; idx += 256) smW2[idx] = W2[idx];
    int wid = t >> 6, l = t & 63;
    int n = blockIdx.x * 4 + wid;  // grid exact: 25000*4 == N_NODES

    smA[wid][l] = elu_f(s1[n * 8 + (l >> 3)] * W1[l] + b1[l]);
    __syncthreads();

    float acc0 = 0.f, acc1 = 0.f;
    const float4* a4 = (const float4*)smA[wid];
#pragma unroll
    for (int kb = 0; kb < 16; ++kb) {
        float4 av = a4[kb];  // broadcast read: all lanes same address
        float ak[4] = {av.x, av.y, av.z, av.w};
#pragma unroll
        for (int u = 0; u < 4; ++u) {
            int k = kb * 4 + u;
            acc0 += ak[u] * smW2[k * 128 + l];
            acc1 += ak[u] * smW2[k * 128 + 64 + l];
        }
    }
    h2p[n * 64 + l] = __floats2half2_rn(acc0, acc1);

    float pSA = acc0 * as2[l];
    float pSB = acc1 * as2[64 + l];
    float pDA = acc0 * ad2[l];
    float pDB = acc1 * ad2[64 + l];
#pragma unroll
    for (int d = 1; d < 16; d <<= 1) {
        pSA += __shfl_xor(pSA, d, 64);
        pSB += __shfl_xor(pSB, d, 64);
        pDA += __shfl_xor(pDA, d, 64);
        pDB += __shfl_xor(pDB, d, 64);
    }
    if ((l & 15) == 0) {
        int h = l >> 4;
        ap[n * 4 + h] = make_float2(pSA, pSB);
        dp[n * 4 + h] = make_float2(pDA, pDB);
    }
}

// ---- Layer 2 aggregation + head-mean + pooled accumulation.
__global__ __launch_bounds__(256) void k_layer2(
    const __half2* __restrict__ h2p, const float2* __restrict__ ap,
    const float2* __restrict__ dp, const int* __restrict__ off,
    const int* __restrict__ csr, const int* __restrict__ batch,
    float* __restrict__ pool) {
    __shared__ float smv[4][16];
    __shared__ int smg[4];
    int t = threadIdx.x;
    int wid = t >> 6, l = t & 63;
    int n = blockIdx.x * 4 + wid;  // grid exact
    int hA = l >> 4;
    float2 ad = dp[n * 4 + hA];

    float2 an = ap[n * 4 + hA];
    float wA = __expf(lrelu(an.x + ad.x));
    float wB = __expf(lrelu(an.y + ad.y));
    float2 hn = __half22float2(h2p[n * 64 + l]);
    float accA = wA * hn.x;
    float accB = wB * hn.y;
    float denA = wA, denB = wB;

    int b = off[n];
    int deg = off[n + 1] - b;
    for (int base = 0; base < deg; base += 64) {
        int rem = deg - base;
        if (rem > 64) rem = 64;
        int sl = (l < rem) ? csr[b + base + l] : 0;  // one coalesced load / chunk
        int j = 0;
        for (; j + 4 <= rem; j += 4) {
            int s0 = __shfl(sl, j, 64);
            int s1i = __shfl(sl, j + 1, 64);
            int s2i = __shfl(sl, j + 2, 64);
            int s3i = __shfl(sl, j + 3, 64);
            float2 p0 = ap[s0 * 4 + hA];
            float2 p1 = ap[s1i * 4 + hA];
            float2 p2 = ap[s2i * 4 + hA];
            float2 p3 = ap[s3i * 4 + hA];
            float2 g0 = __half22float2(h2p[s0 * 64 + l]);
            float2 g1 = __half22float2(h2p[s1i * 64 + l]);
            float2 g2 = __half22float2(h2p[s2i * 64 + l]);
            float2 g3 = __half22float2(h2p[s3i * 64 + l]);
            float e0 = __expf(lrelu(p0.x + ad.x)), f0 = __expf(lrelu(p0.y + ad.y));
            float e1 = __expf(lrelu(p1.x + ad.x)), f1 = __expf(lrelu(p1.y + ad.y));
            float e2 = __expf(lrelu(p2.x + ad.x)), f2 = __expf(lrelu(p2.y + ad.y));
            float e3 = __expf(lrelu(p3.x + ad.x)), f3 = __expf(lrelu(p3.y + ad.y));
            accA += e0 * g0.x; accB += f0 * g0.y;
            accA += e1 * g1.x; accB += f1 * g1.y;
            accA += e2 * g2.x; accB += f2 * g2.y;
            accA += e3 * g3.x; accB += f3 * g3.y;
            denA += (e0 + e1) + (e2 + e3);
            denB += (f0 + f1) + (f2 + f3);
        }
        for (; j < rem; ++j) {
            int s = __shfl(sl, j, 64);
            float2 p = ap[s * 4 + hA];
            float2 g = __half22float2(h2p[s * 64 + l]);
            float eA = __expf(lrelu(p.x + ad.x));
            float eB = __expf(lrelu(p.y + ad.y));
            accA += eA * g.x; accB += eB * g.y;
            denA += eA; denB += eB;
        }
    }
    float v = accA / denA + accB / denB;
    v += __shfl_xor(v, 16, 64);
    v += __shfl_xor(v, 32, 64);
    v *= 0.125f;  // mean over 8 heads
    if (l < 16) smv[wid][l] = v;
    if (l == 0) smg[wid] = batch[n];
    __syncthreads();
    if (t < 64) {
        int w = t >> 4, c = t & 15;
        int g = smg[w];
        bool leader = true;
        for (int w2 = 0; w2 < w; ++w2)
            if (smg[w2] == g) { leader = false; break; }
        if (leader) {
            float s = smv[w][c];
            for (int w2 = w + 1; w2 < 4; ++w2)
                if (smg[w2] == g) s += smv[w2][c];
            atomicAdd(&pool[g * 16 + c], s);
        }
    }
}

// ---- final: pooled mean (+b2) @ Wfc + bfc -> [64,4]
__global__ void k_final(const float* __restrict__ pool, const int* __restrict__ cnt,
                        const float* __restrict__ b2, const float* __restrict__ Wfc,
                        const float* __restrict__ bfc, float* __restrict__ out) {
    int t = threadIdx.x;
    int g = t >> 2, k = t & 3;
    float c = (float)(cnt[g] > 0 ? cnt[g] : 1);
    float acc = bfc[k];
#pragma unroll
    for (int ci = 0; ci < 16; ++ci)
        acc += (pool[g * 16 + ci] / c + b2[ci]) * Wfc[ci * 4 + k];
    out[g * 4 + k] = acc;
}

extern "C" void kernel_launch(void* const* d_in, const int* in_sizes, int n_in,
                              void* d_out, int out_size, void* d_ws, size_t ws_size,
                              hipStream_t stream) {
    const float* x   = (const float*)d_in[0];
    const float* W1  = (const float*)d_in[1];
    const float* as1 = (const float*)d_in[2];
    const float* ad1 = (const float*)d_in[3];
    const float* b1  = (const float*)d_in[4];
    const float* W2  = (const float*)d_in[5];
    const float* as2 = (const float*)d_in[6];
    const float* ad2 = (const float*)d_in[7];
    const float* b2  = (const float*)d_in[8];
    const float* Wfc = (const float*)d_in[9];
    const float* bfc = (const float*)d_in[10];
    const int* ei    = (const int*)d_in[11];
    const int* batch = (const int*)d_in[12];
    const int* srcv  = ei;             // edge_index[0]
    const int* dstv  = ei + N_EDGES;   // edge_index[1]

    char* ws = (char*)d_ws;
    size_t o = 0;
    auto alloc = [&](size_t bytes) {
        void* p = ws + o;
        o += (bytes + 255) & ~(size_t)255;
        return p;
    };
    // zero-region first (one memset): cnt, pool, gbin_cursor
    int*    cnt     = (int*)alloc(64 * 4);
    float*  pool    = (float*)alloc(64 * 16 * 4);
    int*    gbin    = (int*)alloc(NBIN * 4);
    size_t  zbytes  = o;
    int*    bin_base= (int*)alloc((NBIN + 1) * 4);
    int*    off     = (int*)alloc((size_t)(N_NODES + 1) * 4);
    int*    csr     = (int*)alloc((size_t)N_EDGES * 4);
    float*  s1      = (float*)alloc((size_t)N_NODES * 8 * 4);
    // union region: binned (pass A/B only) aliases h2p/ap/dp (gemm onward)
    char*   ubase   = (char*)alloc((size_t)N_NODES * 64 * 4 + (size_t)N_NODES * 4 * 8 * 2);
    int2*   binned  = (int2*)ubase;                                   // 25.7 MB
    __half2* h2p    = (__half2*)ubase;                                // 25.6 MB
    float2* ap      = (float2*)(ubase + (size_t)N_NODES * 64 * 4);
    float2* dp      = (float2*)(ubase + (size_t)N_NODES * 64 * 4 + (size_t)N_NODES * 4 * 8);

    hipMemsetAsync(d_ws, 0, zbytes, stream);

    int nbA = (N_EDGES + EPB - 1) / EPB;   // 391

    k_binA<<<nbA, 256, 0, stream>>>(srcv, dstv, batch, gbin, cnt, binned);
    k_binscan<<<1, 256, 0, stream>>>(gbin, bin_base);
    k_binB<<<NBIN, 1024, 0, stream>>>(binned, gbin, bin_base, off, csr);
    k_layer1<<<N_NODES / 16, 256, 0, stream>>>(x, W1, as1, ad1, off, csr, s1);
    k_gemm<<<N_NODES / 4, 256, 0, stream>>>(s1, W1, b1, W2, as2, ad2, h2p, ap, dp);
    k_layer2<<<N_NODES / 4, 256, 0, stream>>>(h2p, ap, dp, off, csr, batch, pool);
    k_final<<<1, 256, 0, stream>>>(pool, cnt, b2, Wfc, bfc, (float*)d_out);
}

// Round 6
// 319.010 us; speedup vs baseline: 3.7091x; 1.0885x over previous
//
#include <hip/hip_runtime.h>
#include <hip/hip_fp16.h>

#define N_NODES  100000
#define N_EDGES  1600000
#define N_GRAPHS 64

#define BINSH  9
#define NBIN   196          // ceil(100000 / 512)
#define BINCAP 16384        // Poisson(8163) max ~8.6K; 2x headroom
#define EPB    4096         // edges per block in k_binA

__device__ __forceinline__ float lrelu(float v) { return v > 0.f ? v : 0.2f * v; }
__device__ __forceinline__ float elu_f(float v) { return v > 0.f ? v : __expf(v) - 1.f; }
__device__ __forceinline__ float rdlane_f(float v, int lane) {
    return __int_as_float(__builtin_amdgcn_readlane(__float_as_int(v), lane));
}

// ---- Pass A: coarse-bin edges (dst>>9) into per-bin regions, coalesced runs.
// Also folds in the graph-size histogram over nodes.
__global__ __launch_bounds__(256) void k_binA(
    const int* __restrict__ src, const int* __restrict__ dst,
    const int* __restrict__ batch, int* __restrict__ gbin_cursor,
    int* __restrict__ cnt, int2* __restrict__ binned) {
    __shared__ int hist[NBIN], lexcl[NBIN], runbase[NBIN], lcur[NBIN];
    __shared__ int scan[256];
    __shared__ int gh[N_GRAPHS];
    __shared__ int2 stage[EPB];
    int t = threadIdx.x;
    int e0 = blockIdx.x * EPB;
    for (int b = t; b < NBIN; b += 256) hist[b] = 0;
    if (t < N_GRAPHS) gh[t] = 0;
    __syncthreads();
    int nid = blockIdx.x * 256 + t;
    if (nid < N_NODES) atomicAdd(&gh[batch[nid]], 1);
    for (int i = t; i < EPB; i += 256) {
        int e = e0 + i;
        if (e < N_EDGES) atomicAdd(&hist[dst[e] >> BINSH], 1);
    }
    __syncthreads();
    int v = (t < NBIN) ? hist[t] : 0;
    scan[t] = v;
    __syncthreads();
    for (int d = 1; d < 256; d <<= 1) {
        int a = (t >= d) ? scan[t - d] : 0;
        __syncthreads();
        scan[t] += a;
        __syncthreads();
    }
    if (t < NBIN) { lexcl[t] = scan[t] - v; lcur[t] = scan[t] - v; }
    __syncthreads();
    if (t < NBIN && hist[t] > 0) runbase[t] = atomicAdd(&gbin_cursor[t], hist[t]);
    if (t < N_GRAPHS && gh[t]) atomicAdd(&cnt[t], gh[t]);
    __syncthreads();
    for (int i = t; i < EPB; i += 256) {
        int e = e0 + i;
        if (e < N_EDGES) {
            int d = dst[e];
            int b = d >> BINSH;
            int p = atomicAdd(&lcur[b], 1);
            stage[p] = make_int2(src[e], d);
        }
    }
    __syncthreads();
    int m = N_EDGES - e0;
    if (m > EPB) m = EPB;
    for (int i = t; i < m; i += 256) {
        int2 pr = stage[i];
        int b = pr.y >> BINSH;
        binned[(size_t)b * BINCAP + runbase[b] + (i - lexcl[b])] = pr;
    }
}

// ---- tiny scan of bin counts -> compact csr bases
__global__ void k_binscan(const int* __restrict__ gbin_cursor, int* __restrict__ bin_base) {
    __shared__ int sm[256];
    int t = threadIdx.x;
    int v = (t < NBIN) ? gbin_cursor[t] : 0;
    sm[t] = v;
    __syncthreads();
    for (int d = 1; d < 256; d <<= 1) {
        int a = (t >= d) ? sm[t - d] : 0;
        __syncthreads();
        sm[t] += a;
        __syncthreads();
    }
    if (t < NBIN) bin_base[t] = sm[t] - v;
    if (t == 0) bin_base[NBIN] = N_EDGES;
}

// ---- Pass B: per-bin counting sort over 512 local nodes -> off[] + csr[].
__global__ __launch_bounds__(1024) void k_binB(
    const int2* __restrict__ binned, const int* __restrict__ gbin_cursor,
    const int* __restrict__ bin_base, int* __restrict__ off, int* __restrict__ csr) {
    __shared__ int hist[512], sc[512];
    int b = blockIdx.x, t = threadIdx.x;
    int count = gbin_cursor[b];
    int ebase = bin_base[b];
    int node0 = b << BINSH;
    const int2* my = binned + (size_t)b * BINCAP;
    if (t < 512) hist[t] = 0;
    __syncthreads();
    for (int i = t; i < count; i += 1024) atomicAdd(&hist[my[i].y - node0], 1);
    __syncthreads();
    int v = (t < 512) ? hist[t] : 0;
    if (t < 512) sc[t] = v;
    __syncthreads();
    for (int d = 1; d < 512; d <<= 1) {
        int a = (t < 512 && t >= d) ? sc[t - d] : 0;
        __syncthreads();
        if (t < 512) sc[t] += a;
        __syncthreads();
    }
    if (t < 512) {
        int n = node0 + t;
        if (n < N_NODES) off[n] = ebase + sc[t] - v;
        hist[t] = sc[t] - v;  // becomes the local cursor
    }
    if (b == 0 && t == 0) off[N_NODES] = N_EDGES;
    __syncthreads();
    for (int i = t; i < count; i += 1024) {
        int2 pr = my[i];
        int p = atomicAdd(&hist[pr.y - node0], 1);
        csr[ebase + p] = pr.x;
    }
}

// ---- Fused Layer1 + GEMM + attention epilogue. Block = 256, 16 nodes/block.
// Phase 1: rank-1 GAT (16 lanes/node) -> smS1.  Phase 2: per wave, 4 nodes
// sequentially: elu row -> readlane-broadcast x packed-W2 LDS float4 GEMM.
__global__ __launch_bounds__(256) void k_l1gemm(
    const float* __restrict__ x, const float* __restrict__ W1,
    const float* __restrict__ as1, const float* __restrict__ ad1,
    const float* __restrict__ b1, const float* __restrict__ W2,
    const float* __restrict__ as2, const float* __restrict__ ad2,
    const int* __restrict__ off, const int* __restrict__ csr,
    __half2* __restrict__ h2p, float2* __restrict__ ap, float2* __restrict__ dp) {
    __shared__ float4 smW4[32 * 64];   // {W2[2k][l], W2[2k][64+l], W2[2k+1][l], W2[2k+1][64+l]}
    __shared__ float smS1[16][8];
    __shared__ float smws[8], smwd[8];
    int t = threadIdx.x;
    // stage packed W2
    for (int idx = t; idx < 2048; idx += 256) {
        int k2 = idx >> 6, ll = idx & 63;
        smW4[idx] = make_float4(W2[(2 * k2) * 128 + ll], W2[(2 * k2) * 128 + 64 + ll],
                                W2[(2 * k2 + 1) * 128 + ll], W2[(2 * k2 + 1) * 128 + 64 + ll]);
    }
    if (t < 8) {
        float s = 0.f, d = 0.f;
        for (int c = 0; c < 8; ++c) {
            float w = W1[t * 8 + c];
            s += w * as1[t * 8 + c];
            d += w * ad1[t * 8 + c];
        }
        smws[t] = s;
        smwd[t] = d;
    }
    __syncthreads();

    // ---- phase 1: layer 1 for 16 nodes (16 lanes each)
    {
        int nl = t >> 4, c = t & 15;
        int n = blockIdx.x * 16 + nl;   // grid exact: 6250*16 == N_NODES
        float ws[8], wd[8];
#pragma unroll
        for (int h = 0; h < 8; ++h) { ws[h] = smws[h]; wd[h] = smwd[h]; }
        float xn = x[n];
        float num[8], den[8];
#pragma unroll
        for (int h = 0; h < 8; ++h) { num[h] = 0.f; den[h] = 0.f; }
        if (c == 0) {  // self loop
#pragma unroll
            for (int h = 0; h < 8; ++h) {
                float w = __expf(lrelu(xn * ws[h] + xn * wd[h]));
                den[h] = w;
                num[h] = w * xn;
            }
        }
        int b = off[n], e = off[n + 1];
        for (int i = b + c; i < e; i += 16) {
            int s = csr[i];
            float xs = x[s];
#pragma unroll
            for (int h = 0; h < 8; ++h) {
                float w = __expf(lrelu(xs * ws[h] + xn * wd[h]));
                den[h] += w;
                num[h] += w * xs;
            }
        }
#pragma unroll
        for (int d = 1; d < 16; d <<= 1) {
#pragma unroll
            for (int h = 0; h < 8; ++h) {
                num[h] += __shfl_xor(num[h], d, 64);
                den[h] += __shfl_xor(den[h], d, 64);
            }
        }
        if (c == 0) {
#pragma unroll
            for (int h = 0; h < 8; ++h) smS1[nl][h] = num[h] / den[h];
        }
    }
    __syncthreads();

    // ---- phase 2: gemm for 4 nodes per wave
    int wid = t >> 6, l = t & 63;
    float w1l = W1[l], b1l = b1[l];
    float asA = as2[l], asB = as2[64 + l], adA = ad2[l], adB = ad2[64 + l];
    for (int q = 0; q < 4; ++q) {
        int nl = wid * 4 + q;
        int n = blockIdx.x * 16 + nl;
        float a = elu_f(smS1[nl][l >> 3] * w1l + b1l);
        float acc0 = 0.f, acc1 = 0.f;
#pragma unroll
        for (int k2 = 0; k2 < 32; ++k2) {
            float4 wv = smW4[k2 * 64 + l];
            float a0 = rdlane_f(a, 2 * k2);
            float a1 = rdlane_f(a, 2 * k2 + 1);
            acc0 += a0 * wv.x + a1 * wv.z;
            acc1 += a0 * wv.y + a1 * wv.w;
        }
        h2p[n * 64 + l] = __floats2half2_rn(acc0, acc1);

        float pSA = acc0 * asA;
        float pSB = acc1 * asB;
        float pDA = acc0 * adA;
        float pDB = acc1 * adB;
#pragma unroll
        for (int d = 1; d < 16; d <<= 1) {
            pSA += __shfl_xor(pSA, d, 64);
            pSB += __shfl_xor(pSB, d, 64);
            pDA += __shfl_xor(pDA, d, 64);
            pDB += __shfl_xor(pDB, d, 64);
        }
        if ((l & 15) == 0) {
            int h = l >> 4;
            ap[n * 4 + h] = make_float2(pSA, pSB);
            dp[n * 4 + h] = make_float2(pDA, pDB);
        }
    }
}

// ---- Layer 2 aggregation. One wave per destination node.
// Channel mapping: lane l owns (h=l>>4, c=l&15) and (h+4, c).
// Weight phase dedup: lane (j=l>>3, h=l&7) computes w for edge g+j, head h
// -> ONE v_exp per 8 edges; broadcast back via 2 bpermutes/edge.
// Denominator via per-lane wsum + 3 xor-shuffles at the end.
__global__ __launch_bounds__(256) void k_layer2(
    const __half2* __restrict__ h2p, const float2* __restrict__ ap,
    const float2* __restrict__ dp, const int* __restrict__ off,
    const int* __restrict__ csr, const int* __restrict__ batch,
    float* __restrict__ pool) {
    __shared__ float smv[4][16];
    __shared__ int smg[4];
    const float* apf = (const float*)ap;   // flat: node*8 + 2*(h&3) + (h>>2)
    const float* dpf = (const float*)dp;
    int t = threadIdx.x;
    int wid = t >> 6, l = t & 63;
    int n = blockIdx.x * 4 + wid;  // grid exact
    int hA = l >> 4;               // channel-group head
    int hh = l & 7;                // weight-phase head
    int j8 = l >> 3;               // weight-phase edge slot
    int fidx = 2 * (hh & 3) + (hh >> 2);
    float dn = dpf[n * 8 + fidx];  // adst[n][hh]

    // self loop (heads hA, hA+4)
    float2 ad = dp[n * 4 + hA];
    float2 an = ap[n * 4 + hA];
    float wA = __expf(lrelu(an.x + ad.x));
    float wB = __expf(lrelu(an.y + ad.y));
    float2 hn = __half22float2(h2p[n * 64 + l]);
    float accA = wA * hn.x, accB = wB * hn.y;
    float denTA = wA, denTB = wB;
    float wsum = 0.f;

    int b = off[n];
    int deg = off[n + 1] - b;
    for (int base = 0; base < deg; base += 64) {
        int rem = deg - base;
        if (rem > 64) rem = 64;
        int sl = (l < rem) ? csr[b + base + l] : 0;  // one coalesced load / chunk
        int g = 0;
        for (; g + 8 <= rem; g += 8) {
            // weight phase: 64 distinct (edge,head) -> one exp
            int sg = __shfl(sl, g + j8, 64);
            float w = __expf(lrelu(apf[sg * 8 + fidx] + dn));
            wsum += w;
#pragma unroll
            for (int j2 = 0; j2 < 8; ++j2) {
                int s = __builtin_amdgcn_readlane(sl, g + j2);   // SGPR src id
                float wa = __shfl(w, j2 * 8 + hA, 64);
                float wb = __shfl(w, j2 * 8 + hA + 4, 64);
                float2 gg = __half22float2(h2p[s * 64 + l]);
                accA = fmaf(wa, gg.x, accA);
                accB = fmaf(wb, gg.y, accB);
            }
        }
        if (g < rem) {  // partial group (1..7 edges)
            int cnt = rem - g;
            int jj = (j8 < cnt) ? j8 : 0;
            int sg = __shfl(sl, g + jj, 64);
            float w = (j8 < cnt) ? __expf(lrelu(apf[sg * 8 + fidx] + dn)) : 0.f;
            wsum += w;
            for (int j2 = 0; j2 < cnt; ++j2) {
                int s = __builtin_amdgcn_readlane(sl, g + j2);
                float wa = __shfl(w, j2 * 8 + hA, 64);
                float wb = __shfl(w, j2 * 8 + hA + 4, 64);
                float2 gg = __half22float2(h2p[s * 64 + l]);
                accA = fmaf(wa, gg.x, accA);
                accB = fmaf(wb, gg.y, accB);
            }
        }
    }
    // den[h] = sum over edge slots (lanes h, h+8, ..., h+56)
    wsum += __shfl_xor(wsum, 8, 64);
    wsum += __shfl_xor(wsum, 16, 64);
    wsum += __shfl_xor(wsum, 32, 64);
    float denA = denTA + __shfl(wsum, hA, 64);
    float denB = denTB + __shfl(wsum, hA + 4, 64);

    float v = accA / denA + accB / denB;
    v += __shfl_xor(v, 16, 64);
    v += __shfl_xor(v, 32, 64);
    v *= 0.125f;  // mean over 8 heads
    if (l < 16) smv[wid][l] = v;
    if (l == 0) smg[wid] = batch[n];
    __syncthreads();
    if (t < 64) {
        int w = t >> 4, c = t & 15;
        int g = smg[w];
        bool leader = true;
        for (int w2 = 0; w2 < w; ++w2)
            if (smg[w2] == g) { leader = false; break; }
        if (leader) {
            float s = smv[w][c];
            for (int w2 = w + 1; w2 < 4; ++w2)
                if (smg[w2] == g) s += smv[w2][c];
            atomicAdd(&pool[g * 16 + c], s);
        }
    }
}

// ---- final: pooled mean (+b2) @ Wfc + bfc -> [64,4]
__global__ void k_final(const float* __restrict__ pool, const int* __restrict__ cnt,
                        const float* __restrict__ b2, const float* __restrict__ Wfc,
                        const float* __restrict__ bfc, float* __restrict__ out) {
    int t = threadIdx.x;
    int g = t >> 2, k = t & 3;
    float c = (float)(cnt[g] > 0 ? cnt[g] : 1);
    float acc = bfc[k];
#pragma unroll
    for (int ci = 0; ci < 16; ++ci)
        acc += (pool[g * 16 + ci] / c + b2[ci]) * Wfc[ci * 4 + k];
    out[g * 4 + k] = acc;
}

extern "C" void kernel_launch(void* const* d_in, const int* in_sizes, int n_in,
                              void* d_out, int out_size, void* d_ws, size_t ws_size,
                              hipStream_t stream) {
    const float* x   = (const float*)d_in[0];
    const float* W1  = (const float*)d_in[1];
    const float* as1 = (const float*)d_in[2];
    const float* ad1 = (const float*)d_in[3];
    const float* b1  = (const float*)d_in[4];
    const float* W2  = (const float*)d_in[5];
    const float* as2 = (const float*)d_in[6];
    const float* ad2 = (const float*)d_in[7];
    const float* b2  = (const float*)d_in[8];
    const float* Wfc = (const float*)d_in[9];
    const float* bfc = (const float*)d_in[10];
    const int* ei    = (const int*)d_in[11];
    const int* batch = (const int*)d_in[12];
    const int* srcv  = ei;             // edge_index[0]
    const int* dstv  = ei + N_EDGES;   // edge_index[1]

    char* ws = (char*)d_ws;
    size_t o = 0;
    auto alloc = [&](size_t bytes) {
        void* p = ws + o;
        o += (bytes + 255) & ~(size_t)255;
        return p;
    };
    // zero-region first (one memset): cnt, pool, gbin_cursor
    int*    cnt     = (int*)alloc(64 * 4);
    float*  pool    = (float*)alloc(64 * 16 * 4);
    int*    gbin    = (int*)alloc(NBIN * 4);
    size_t  zbytes  = o;
    int*    bin_base= (int*)alloc((NBIN + 1) * 4);
    int*    off     = (int*)alloc((size_t)(N_NODES + 1) * 4);
    int*    csr     = (int*)alloc((size_t)N_EDGES * 4);
    // union region: binned (CSR build only) aliases h2p/ap/dp (l1gemm onward)
    char*   ubase   = (char*)alloc((size_t)N_NODES * 64 * 4 + (size_t)N_NODES * 4 * 8 * 2);
    int2*   binned  = (int2*)ubase;
    __half2* h2p    = (__half2*)ubase;
    float2* ap      = (float2*)(ubase + (size_t)N_NODES * 64 * 4);
    float2* dp      = (float2*)(ubase + (size_t)N_NODES * 64 * 4 + (size_t)N_NODES * 4 * 8);

    hipMemsetAsync(d_ws, 0, zbytes, stream);

    int nbA = (N_EDGES + EPB - 1) / EPB;   // 391

    k_binA<<<nbA, 256, 0, stream>>>(srcv, dstv, batch, gbin, cnt, binned);
    k_binscan<<<1, 256, 0, stream>>>(gbin, bin_base);
    k_binB<<<NBIN, 1024, 0, stream>>>(binned, gbin, bin_base, off, csr);
    k_l1gemm<<<N_NODES / 16, 256, 0, stream>>>(x, W1, as1, ad1, b1, W2, as2, ad2,
                                               off, csr, h2p, ap, dp);
    k_layer2<<<N_NODES / 4, 256, 0, stream>>>(h2p, ap, dp, off, csr, batch, pool);
    k_final<<<1, 256, 0, stream>>>(pool, cnt, b2, Wfc, bfc, (float*)d_out);
}